// Round 1
// baseline (219.253 us; speedup 1.0000x reference)
//
#include <hip/hip_runtime.h>
#include <math.h>

// MOTIP criterion: Hungarian matching (JV shortest augmenting path) + losses.
// F=128 frames, N=300 preds, M=32 targets, C=2 classes, K1=512 id classes.

constexpr int F_FRAMES = 128;
constexpr int N_PRED   = 300;
constexpr int M_TGT    = 32;
constexpr int K_ID     = 512;
constexpr int NSLOT    = 5;    // ceil(300/64)

// ---------- helpers: 5-element register-array dynamic access (keep in VGPRs) ----------
__device__ __forceinline__ int sel5i(const int a[NSLOT], int s) {
    int r = a[0];
    r = (s == 1) ? a[1] : r;
    r = (s == 2) ? a[2] : r;
    r = (s == 3) ? a[3] : r;
    r = (s == 4) ? a[4] : r;
    return r;
}
__device__ __forceinline__ void set5i(int a[NSLOT], int s, int val) {
    if (s == 0) a[0] = val;
    if (s == 1) a[1] = val;
    if (s == 2) a[2] = val;
    if (s == 3) a[3] = val;
    if (s == 4) a[4] = val;
}

// ---------------------------------------------------------------------------
// Kernel 1: per-frame cost matrix (into LDS) + Jonker-Volgenant assignment.
// One block = one frame, blockDim = 64 (one wave).
// Solves rows = targets (32), cols = predictions (300); writes pred_idx[f][m].
// Solver arithmetic in fp64 to mirror the float64 CPU reference solver.
// ---------------------------------------------------------------------------
__global__ __launch_bounds__(64) void hungarian_kernel(
    const float* __restrict__ pl,      // [F,N,2]
    const float* __restrict__ pb,      // [F,N,4]
    const int*   __restrict__ labels,  // [F,M]
    const float* __restrict__ tb,      // [F,M,4]
    int* __restrict__ pred_idx)        // [F,M]
{
    const int f    = blockIdx.x;
    const int lane = threadIdx.x;

    __shared__ float  s_cost[M_TGT * N_PRED];   // 38400 B
    __shared__ float  s_tb[M_TGT][4];           // target cxcywh
    __shared__ float  s_txy[M_TGT][4];          // target xyxy
    __shared__ float  s_ta[M_TGT];              // target area
    __shared__ int    s_lab[M_TGT];
    __shared__ double s_u[M_TGT];               // row potentials

    if (lane < M_TGT) {
        const float* tp = tb + ((size_t)f * M_TGT + lane) * 4;
        float cx = tp[0], cy = tp[1], w = tp[2], h = tp[3];
        s_tb[lane][0] = cx; s_tb[lane][1] = cy; s_tb[lane][2] = w; s_tb[lane][3] = h;
        float x0 = cx - 0.5f * w, y0 = cy - 0.5f * h;
        float x1 = cx + 0.5f * w, y1 = cy + 0.5f * h;
        s_txy[lane][0] = x0; s_txy[lane][1] = y0; s_txy[lane][2] = x1; s_txy[lane][3] = y1;
        s_ta[lane] = (x1 - x0) * (y1 - y0);
        s_lab[lane] = labels[f * M_TGT + lane];
        s_u[lane] = 0.0;
    }
    __syncthreads();

    // ---- per-slot prediction data (registers) ----
    float P0[NSLOT], P1[NSLOT];
    float AX0[NSLOT], AY0[NSLOT], AX1[NSLOT], AY1[NSLOT], AR[NSLOT];
    float BCX[NSLOT], BCY[NSLOT], BW[NSLOT], BH[NSLOT];
#pragma unroll
    for (int s = 0; s < NSLOT; ++s) {
        int n = s * 64 + lane;
        P0[s] = 0.f; P1[s] = 0.f; AX0[s] = AY0[s] = AX1[s] = AY1[s] = AR[s] = 0.f;
        BCX[s] = BCY[s] = BW[s] = BH[s] = 0.f;
        if (n < N_PRED) {
            float l0  = pl[((size_t)f * N_PRED + n) * 2 + 0];
            float l1v = pl[((size_t)f * N_PRED + n) * 2 + 1];
            float mx  = fmaxf(l0, l1v);
            float e0  = expf(l0 - mx), e1 = expf(l1v - mx);
            float inv = 1.0f / (e0 + e1);
            P0[s] = e0 * inv; P1[s] = e1 * inv;
            const float* bp = pb + ((size_t)f * N_PRED + n) * 4;
            float cx = bp[0], cy = bp[1], w = bp[2], h = bp[3];
            BCX[s] = cx; BCY[s] = cy; BW[s] = w; BH[s] = h;
            AX0[s] = cx - 0.5f * w; AY0[s] = cy - 0.5f * h;
            AX1[s] = cx + 0.5f * w; AY1[s] = cy + 0.5f * h;
            AR[s] = (AX1[s] - AX0[s]) * (AY1[s] - AY0[s]);
        }
    }

    // ---- fill cost matrix: C[m][n] = 2*(-prob[label]) + 5*L1 + 2*(-giou) ----
    for (int m = 0; m < M_TGT; ++m) {
        float tcx = s_tb[m][0], tcy = s_tb[m][1], tw = s_tb[m][2], th = s_tb[m][3];
        float tx0 = s_txy[m][0], ty0 = s_txy[m][1], tx1 = s_txy[m][2], ty1 = s_txy[m][3];
        float ta  = s_ta[m];
        int   lab = s_lab[m];
#pragma unroll
        for (int s = 0; s < NSLOT; ++s) {
            int n = s * 64 + lane;
            if (n < N_PRED) {
                float ccls = -((lab == 0) ? P0[s] : P1[s]);
                float cl1  = fabsf(BCX[s] - tcx) + fabsf(BCY[s] - tcy)
                           + fabsf(BW[s] - tw)  + fabsf(BH[s] - th);
                float ltx = fmaxf(AX0[s], tx0), lty = fmaxf(AY0[s], ty0);
                float rbx = fminf(AX1[s], tx1), rby = fminf(AY1[s], ty1);
                float iw = fmaxf(rbx - ltx, 0.f), ih = fmaxf(rby - lty, 0.f);
                float inter = iw * ih;
                float uni   = AR[s] + ta - inter;
                float iou   = inter / uni;
                float Ltx = fminf(AX0[s], tx0), Lty = fminf(AY0[s], ty0);
                float Rbx = fmaxf(AX1[s], tx1), Rby = fmaxf(AY1[s], ty1);
                float cw = fmaxf(Rbx - Ltx, 0.f), ch = fmaxf(Rby - Lty, 0.f);
                float ac = cw * ch;
                float giou = iou - (ac - uni) / ac;
                s_cost[m * N_PRED + n] = 2.f * ccls + 5.f * cl1 - 2.f * giou;
            }
        }
    }
    __syncthreads();

    // ---- JV solve: rows = targets (32) assigned to cols = preds (300) ----
    double v[NSLOT], minv[NSLOT];
    int way[NSLOT], pcol[NSLOT], used[NSLOT];
#pragma unroll
    for (int s = 0; s < NSLOT; ++s) { v[s] = 0.0; pcol[s] = -1; }

    for (int i = 0; i < M_TGT; ++i) {
#pragma unroll
        for (int s = 0; s < NSLOT; ++s) { minv[s] = INFINITY; way[s] = -1; used[s] = 0; }
        int j0 = -1;   // -1 == virtual start column
        int i0 = i;
        while (true) {
            double u_i0 = s_u[i0];
            // scan free columns: relax with current row i0
#pragma unroll
            for (int s = 0; s < NSLOT; ++s) {
                int j = s * 64 + lane;
                if (j < N_PRED && !used[s]) {
                    double cur = (double)s_cost[i0 * N_PRED + j] - u_i0 - v[s];
                    if (cur < minv[s]) { minv[s] = cur; way[s] = j0; }
                }
            }
            // argmin over free columns (lowest index on ties, like np.argmin)
            double bval = INFINITY; int bidx = 0x7fffffff;
#pragma unroll
            for (int s = 0; s < NSLOT; ++s) {
                int j = s * 64 + lane;
                if (j < N_PRED && !used[s] && minv[s] < bval) { bval = minv[s]; bidx = j; }
            }
#pragma unroll
            for (int off = 32; off > 0; off >>= 1) {
                double oval = __shfl_xor(bval, off);
                int    oidx = __shfl_xor(bidx, off);
                if (oval < bval || (oval == bval && oidx < bidx)) { bval = oval; bidx = oidx; }
            }
            double delta = bval;
            int    j1    = bidx;
            // potential update: used cols -> v down / u(row) up; free -> minv down
#pragma unroll
            for (int s = 0; s < NSLOT; ++s) {
                int j = s * 64 + lane;
                if (j < N_PRED) {
                    if (used[s]) { v[s] -= delta; s_u[pcol[s]] += delta; }
                    else         { minv[s] -= delta; }
                }
            }
            if (lane == 0) s_u[i] += delta;   // virtual column carries row i
            __syncthreads();                   // order LDS u writes before next read
            // fetch p[j1], mark j1 used
            int slot1 = j1 >> 6, lane1 = j1 & 63;
            int pj1 = __shfl(sel5i(pcol, slot1), lane1);
            if (lane == lane1) set5i(used, slot1, 1);
            j0 = j1;
            if (pj1 < 0) break;
            i0 = pj1;
        }
        // augment along the way[] chain
        int j = j0;
        while (true) {
            int slot = j >> 6, ln = j & 63;
            int wj = __shfl(sel5i(way, slot), ln);
            int newp;
            if (wj < 0) newp = i;
            else        newp = __shfl(sel5i(pcol, wj >> 6), wj & 63);
            if (lane == ln) set5i(pcol, slot, newp);
            if (wj < 0) break;
            j = wj;
        }
    }

    // write col4row: pred_idx[f][row] = col
#pragma unroll
    for (int s = 0; s < NSLOT; ++s) {
        int j = s * 64 + lane;
        if (j < N_PRED && pcol[s] >= 0) pred_idx[f * M_TGT + pcol[s]] = j;
    }
}

// ---------------------------------------------------------------------------
// Kernel 2: per-pair losses. One wave per (f,m) pair; 4 waves/block.
// pair_out[0*4096+p] = L1 sum (4 coords); [1*...] = giou; [2*...] = id NLL.
// ---------------------------------------------------------------------------
__global__ __launch_bounds__(256) void pair_kernel(
    const float* __restrict__ pb,       // [F,N,4]
    const float* __restrict__ il,       // [F,N,K]
    const float* __restrict__ tb,       // [F,M,4]
    const int*   __restrict__ tids,     // [F,M]
    const int*   __restrict__ pred_idx, // [F,M]
    float* __restrict__ pair_out)       // [3, F*M]
{
    const int wave = threadIdx.x >> 6;
    const int lane = threadIdx.x & 63;
    const int pair = blockIdx.x * 4 + wave;     // 0..4095
    const int f = pair >> 5;
    const int m = pair & (M_TGT - 1);

    const int idx = pred_idx[pair];
    const float* base = il + ((size_t)f * N_PRED + idx) * K_ID;

    // logsumexp over 512
    float vals[8];
#pragma unroll
    for (int k = 0; k < 8; ++k) vals[k] = base[k * 64 + lane];
    float mx = -INFINITY;
#pragma unroll
    for (int k = 0; k < 8; ++k) mx = fmaxf(mx, vals[k]);
#pragma unroll
    for (int off = 32; off > 0; off >>= 1) mx = fmaxf(mx, __shfl_xor(mx, off));
    float se = 0.f;
#pragma unroll
    for (int k = 0; k < 8; ++k) se += expf(vals[k] - mx);
#pragma unroll
    for (int off = 32; off > 0; off >>= 1) se += __shfl_xor(se, off);
    float lse = mx + logf(se);

    if (lane == 0) {
        const float* bp = pb + ((size_t)f * N_PRED + idx) * 4;
        const float* tp = tb + ((size_t)f * M_TGT + m) * 4;
        float bcx = bp[0], bcy = bp[1], bw = bp[2], bh = bp[3];
        float tcx = tp[0], tcy = tp[1], tw = tp[2], th = tp[3];
        float l1 = fabsf(bcx - tcx) + fabsf(bcy - tcy) + fabsf(bw - tw) + fabsf(bh - th);
        // pairwise giou
        float ax0 = bcx - 0.5f * bw, ay0 = bcy - 0.5f * bh;
        float ax1 = bcx + 0.5f * bw, ay1 = bcy + 0.5f * bh;
        float tx0 = tcx - 0.5f * tw, ty0 = tcy - 0.5f * th;
        float tx1 = tcx + 0.5f * tw, ty1 = tcy + 0.5f * th;
        float a1 = (ax1 - ax0) * (ay1 - ay0);
        float a2 = (tx1 - tx0) * (ty1 - ty0);
        float iw = fmaxf(fminf(ax1, tx1) - fmaxf(ax0, tx0), 0.f);
        float ih = fmaxf(fminf(ay1, ty1) - fmaxf(ay0, ty0), 0.f);
        float inter = iw * ih;
        float uni = a1 + a2 - inter;
        float iou = inter / uni;
        float cw = fmaxf(fmaxf(ax1, tx1) - fminf(ax0, tx0), 0.f);
        float ch = fmaxf(fmaxf(ay1, ty1) - fminf(ay0, ty0), 0.f);
        float ac = cw * ch;
        float giou = iou - (ac - uni) / ac;
        // id NLL
        int tg = tids[pair];
        float nll = lse - base[tg];
        pair_out[pair]                       = l1;
        pair_out[F_FRAMES * M_TGT + pair]    = giou;
        pair_out[2 * F_FRAMES * M_TGT + pair] = nll;
    }
}

// ---------------------------------------------------------------------------
// Kernel 3: deterministic reduction of 4096x3 partials -> 5 outputs.
// ---------------------------------------------------------------------------
__global__ __launch_bounds__(256) void finalize_kernel(
    const float* __restrict__ pr, float* __restrict__ out)
{
    constexpr int P = F_FRAMES * M_TGT;   // 4096
    float s0 = 0.f, s1 = 0.f, s2 = 0.f;
    for (int i = threadIdx.x; i < P; i += 256) {
        s0 += pr[i];
        s1 += pr[P + i];
        s2 += pr[2 * P + i];
    }
#pragma unroll
    for (int off = 32; off > 0; off >>= 1) {
        s0 += __shfl_xor(s0, off);
        s1 += __shfl_xor(s1, off);
        s2 += __shfl_xor(s2, off);
    }
    __shared__ float w0[4], w1[4], w2[4];
    const int wave = threadIdx.x >> 6, lane = threadIdx.x & 63;
    if (lane == 0) { w0[wave] = s0; w1[wave] = s1; w2[wave] = s2; }
    __syncthreads();
    if (threadIdx.x == 0) {
        float S0 = w0[0] + w0[1] + w0[2] + w0[3];
        float S1 = w1[0] + w1[1] + w1[2] + w1[3];
        float S2 = w2[0] + w2[1] + w2[2] + w2[3];
        float l1  = S0 * (1.f / (P * 4));
        float gl  = 1.f - S1 * (1.f / P);
        float idl = S2 * (1.f / P);
        out[0] = 5.f * l1 + 2.f * gl + 1.f * idl;   // + 2*0 cls
        out[1] = 0.f;
        out[2] = l1;
        out[3] = gl;
        out[4] = idl;
    }
}

extern "C" void kernel_launch(void* const* d_in, const int* in_sizes, int n_in,
                              void* d_out, int out_size, void* d_ws, size_t ws_size,
                              hipStream_t stream) {
    const float* pl     = (const float*)d_in[0];   // pred_logits  [8,16,300,2]
    const float* pb     = (const float*)d_in[1];   // pred_boxes   [8,16,300,4]
    const float* il     = (const float*)d_in[2];   // id_logits    [8,16,300,512]
    const int*   labels = (const int*)d_in[3];     // target_labels [128,32]
    const float* tb     = (const float*)d_in[4];   // target_boxes  [128,32,4]
    const int*   tids   = (const int*)d_in[5];     // target_ids    [128,32]
    float* out = (float*)d_out;

    char* ws = (char*)d_ws;
    int*   pred_idx = (int*)ws;                        // 4096 ints = 16 KB
    float* pair_out = (float*)(ws + 16384);            // 3*4096 floats = 48 KB

    hungarian_kernel<<<F_FRAMES, 64, 0, stream>>>(pl, pb, labels, tb, pred_idx);
    pair_kernel<<<F_FRAMES * M_TGT / 4, 256, 0, stream>>>(pb, il, tb, tids, pred_idx, pair_out);
    finalize_kernel<<<1, 256, 0, stream>>>(pair_out, out);
}

// Round 2
// 169.472 us; speedup vs baseline: 1.2937x; 1.2937x over previous
//
#include <hip/hip_runtime.h>
#include <math.h>

// MOTIP criterion: Hungarian matching (JV with greedy dual-feasible init) + losses.
// F=128 frames, N=300 preds, M=32 targets, C=2 classes, K1=512 id classes.

constexpr int F_FRAMES = 128;
constexpr int N_PRED   = 300;
constexpr int M_TGT    = 32;
constexpr int K_ID     = 512;
constexpr int NSLOT    = 5;     // ceil(300/64)
constexpr int PITCH    = 301;   // LDS row pitch (pad: 13 coprime 32 -> conflict-free 2-lane/row scan)

// ---------- 5-element register-array dynamic access (keep in VGPRs) ----------
__device__ __forceinline__ int sel5i(const int a[NSLOT], int s) {
    int r = a[0];
    r = (s == 1) ? a[1] : r;
    r = (s == 2) ? a[2] : r;
    r = (s == 3) ? a[3] : r;
    r = (s == 4) ? a[4] : r;
    return r;
}
__device__ __forceinline__ float sel5f(const float a[NSLOT], int s) {
    float r = a[0];
    r = (s == 1) ? a[1] : r;
    r = (s == 2) ? a[2] : r;
    r = (s == 3) ? a[3] : r;
    r = (s == 4) ? a[4] : r;
    return r;
}
__device__ __forceinline__ void set5i(int a[NSLOT], int s, int val) {
    if (s == 0) a[0] = val;
    if (s == 1) a[1] = val;
    if (s == 2) a[2] = val;
    if (s == 3) a[3] = val;
    if (s == 4) a[4] = val;
}
// monotone float -> uint mapping (order-preserving, handles negatives)
__device__ __forceinline__ unsigned mono32(float x) {
    unsigned b = __float_as_uint(x);
    return b ^ ((b & 0x80000000u) ? 0xFFFFFFFFu : 0x80000000u);
}

// ---------------------------------------------------------------------------
// Kernel 1: per-frame cost matrix (LDS) + Jonker-Volgenant assignment.
// One block = one frame = one wave (64 threads).
// rows = targets (32), cols = predictions (300); writes pred_idx[f][m].
// Greedy init: u[i] = row min, claim argmin columns; Dijkstra only for
// collision rows. All solver state in registers/shuffles; no barriers in loop.
// ---------------------------------------------------------------------------
__global__ __launch_bounds__(64) void hungarian_kernel(
    const float* __restrict__ pl,      // [F,N,2]
    const float* __restrict__ pb,      // [F,N,4]
    const int*   __restrict__ labels,  // [F,M]
    const float* __restrict__ tb,      // [F,M,4]
    int* __restrict__ pred_idx)        // [F,M]
{
    const int f    = blockIdx.x;
    const int lane = threadIdx.x;

    __shared__ float s_cost[M_TGT * PITCH];     // ~38.5 KB
    __shared__ int   s_claim[N_PRED];
    __shared__ float s_tb[M_TGT][4];            // target cxcywh
    __shared__ float s_txy[M_TGT][4];           // target xyxy
    __shared__ float s_ta[M_TGT];               // target area
    __shared__ int   s_lab[M_TGT];

    if (lane < M_TGT) {
        const float* tp = tb + ((size_t)f * M_TGT + lane) * 4;
        float cx = tp[0], cy = tp[1], w = tp[2], h = tp[3];
        s_tb[lane][0] = cx; s_tb[lane][1] = cy; s_tb[lane][2] = w; s_tb[lane][3] = h;
        float x0 = cx - 0.5f * w, y0 = cy - 0.5f * h;
        float x1 = cx + 0.5f * w, y1 = cy + 0.5f * h;
        s_txy[lane][0] = x0; s_txy[lane][1] = y0; s_txy[lane][2] = x1; s_txy[lane][3] = y1;
        s_ta[lane] = (x1 - x0) * (y1 - y0);
        s_lab[lane] = labels[f * M_TGT + lane];
    }
#pragma unroll
    for (int s = 0; s < NSLOT; ++s) {
        int j = s * 64 + lane;
        if (j < N_PRED) s_claim[j] = 0x7fffffff;
    }
    __syncthreads();

    // ---- per-slot prediction data (registers) ----
    float P0[NSLOT], P1[NSLOT];
    float AX0[NSLOT], AY0[NSLOT], AX1[NSLOT], AY1[NSLOT], AR[NSLOT];
    float BCX[NSLOT], BCY[NSLOT], BW[NSLOT], BH[NSLOT];
#pragma unroll
    for (int s = 0; s < NSLOT; ++s) {
        int n = s * 64 + lane;
        P0[s] = 0.f; P1[s] = 0.f; AX0[s] = AY0[s] = AX1[s] = AY1[s] = AR[s] = 0.f;
        BCX[s] = BCY[s] = BW[s] = BH[s] = 0.f;
        if (n < N_PRED) {
            float l0  = pl[((size_t)f * N_PRED + n) * 2 + 0];
            float l1v = pl[((size_t)f * N_PRED + n) * 2 + 1];
            float mx  = fmaxf(l0, l1v);
            float e0  = expf(l0 - mx), e1 = expf(l1v - mx);
            float inv = 1.0f / (e0 + e1);
            P0[s] = e0 * inv; P1[s] = e1 * inv;
            const float* bp = pb + ((size_t)f * N_PRED + n) * 4;
            float cx = bp[0], cy = bp[1], w = bp[2], h = bp[3];
            BCX[s] = cx; BCY[s] = cy; BW[s] = w; BH[s] = h;
            AX0[s] = cx - 0.5f * w; AY0[s] = cy - 0.5f * h;
            AX1[s] = cx + 0.5f * w; AY1[s] = cy + 0.5f * h;
            AR[s] = (AX1[s] - AX0[s]) * (AY1[s] - AY0[s]);
        }
    }

    // ---- cost fill: C[m][n] = 2*(-prob[label]) + 5*L1 - 2*giou ----
    for (int m = 0; m < M_TGT; ++m) {
        float tcx = s_tb[m][0], tcy = s_tb[m][1], tw = s_tb[m][2], th = s_tb[m][3];
        float tx0 = s_txy[m][0], ty0 = s_txy[m][1], tx1 = s_txy[m][2], ty1 = s_txy[m][3];
        float ta  = s_ta[m];
        int   lab = s_lab[m];
#pragma unroll
        for (int s = 0; s < NSLOT; ++s) {
            int n = s * 64 + lane;
            if (n < N_PRED) {
                float ccls = -((lab == 0) ? P0[s] : P1[s]);
                float cl1  = fabsf(BCX[s] - tcx) + fabsf(BCY[s] - tcy)
                           + fabsf(BW[s] - tw)  + fabsf(BH[s] - th);
                float ltx = fmaxf(AX0[s], tx0), lty = fmaxf(AY0[s], ty0);
                float rbx = fminf(AX1[s], tx1), rby = fminf(AY1[s], ty1);
                float iw = fmaxf(rbx - ltx, 0.f), ih = fmaxf(rby - lty, 0.f);
                float inter = iw * ih;
                float uni   = AR[s] + ta - inter;
                float iou   = inter / uni;
                float Ltx = fminf(AX0[s], tx0), Lty = fminf(AY0[s], ty0);
                float Rbx = fmaxf(AX1[s], tx1), Rby = fmaxf(AY1[s], ty1);
                float cw = fmaxf(Rbx - Ltx, 0.f), ch = fmaxf(Rby - Lty, 0.f);
                float ac = cw * ch;
                float giou = iou - (ac - uni) / ac;
                s_cost[m * PITCH + n] = 2.f * ccls + 5.f * cl1 - 2.f * giou;
            }
        }
    }
    __syncthreads();

    // ---- greedy init: parallel row minima (2 lanes per row, 150 cols each) ----
    {
        int r = lane >> 1, half = lane & 1;
        float bv = INFINITY; int bj = 0;
        const float* crow = s_cost + r * PITCH + half * 150;
        for (int t = 0; t < 150; ++t) {
            float c = crow[t];
            if (c < bv) { bv = c; bj = half * 150 + t; }
        }
        float ov = __shfl_xor(bv, 1);
        int   oj = __shfl_xor(bj, 1);
        if (ov < bv || (ov == bv && oj < bj)) { bv = ov; bj = oj; }
        if (half == 0) atomicMin(&s_claim[bj], r);   // lowest row wins contested col
        __syncthreads();

        // lane l < 32 owns row l: u, assigned?
        float mval = __shfl(bv, 2 * (lane & 31));
        int   midx = __shfl(bj, 2 * (lane & 31));
        float u_new = mval;
        bool assigned = (lane < M_TGT) && (s_claim[midx] == lane);
        unsigned long long blt = __ballot(assigned);
        unsigned assignedMask = (unsigned)(blt & 0xFFFFFFFFull);
        unsigned freeMask = ~assignedMask;

        // pcol from claims
        int pcol[NSLOT];
#pragma unroll
        for (int s = 0; s < NSLOT; ++s) {
            int j = s * 64 + lane;
            pcol[s] = -1;
            if (j < N_PRED) { int c = s_claim[j]; if (c != 0x7fffffff) pcol[s] = c; }
        }
        float v[NSLOT];
#pragma unroll
        for (int s = 0; s < NSLOT; ++s) v[s] = 0.f;
        float u_reg = u_new;   // lane i holds u[i] (i<32); others don't matter

        // ---- Dijkstra phases for unassigned rows only ----
        while (freeMask) {
            int i = __ffs(freeMask) - 1;
            freeMask &= freeMask - 1;

            float minv[NSLOT]; int way[NSLOT]; int used[NSLOT];
#pragma unroll
            for (int s = 0; s < NSLOT; ++s) { minv[s] = INFINITY; way[s] = -1; used[s] = 0; }
            unsigned treeMask = 0;
            int i0 = i, j0 = -1;

            for (int guard = 0; guard < 4096; ++guard) {
                treeMask |= 1u << i0;
                float u_i0 = __shfl(u_reg, i0);
                const float* crow2 = s_cost + i0 * PITCH;
                unsigned bkey = 0xFFFFFFFFu;
#pragma unroll
                for (int s = 0; s < NSLOT; ++s) {
                    int j = s * 64 + lane;
                    if (j < N_PRED && !used[s]) {
                        float cur = crow2[j] - u_i0 - v[s];
                        if (cur < minv[s]) { minv[s] = cur; way[s] = j0; }
                        unsigned key = (mono32(minv[s]) & 0xFFFFFE00u) | (unsigned)j;
                        bkey = min(bkey, key);
                    }
                }
#pragma unroll
                for (int off = 32; off > 0; off >>= 1)
                    bkey = min(bkey, (unsigned)__shfl_xor((int)bkey, off));
                int j1 = bkey & 0x1FF;
                int slot1 = j1 >> 6, lane1 = j1 & 63;
                float delta = __shfl(sel5f(minv, slot1), lane1);   // exact min value

                if (lane < M_TGT && ((treeMask >> lane) & 1)) u_reg += delta;
#pragma unroll
                for (int s = 0; s < NSLOT; ++s) {
                    int j = s * 64 + lane;
                    if (j < N_PRED) { if (used[s]) v[s] -= delta; else minv[s] -= delta; }
                }
                int pj1 = __shfl(sel5i(pcol, slot1), lane1);
                if (lane == lane1) set5i(used, slot1, 1);
                j0 = j1;
                if (pj1 < 0) break;
                i0 = pj1;
            }
            // augment along way[] chain
            int j = j0;
            while (true) {
                int slot = j >> 6, ln = j & 63;
                int wj = __shfl(sel5i(way, slot), ln);
                int newp = (wj < 0) ? i : __shfl(sel5i(pcol, wj >> 6), wj & 63);
                if (lane == ln) set5i(pcol, slot, newp);
                if (wj < 0) break;
                j = wj;
            }
        }

        // write col4row: pred_idx[f][row] = col
#pragma unroll
        for (int s = 0; s < NSLOT; ++s) {
            int j = s * 64 + lane;
            if (j < N_PRED && pcol[s] >= 0) pred_idx[f * M_TGT + pcol[s]] = j;
        }
    }
}

// ---------------------------------------------------------------------------
// Kernel 2: per-pair losses. One wave per (f,m) pair; 4 waves/block.
// ---------------------------------------------------------------------------
__global__ __launch_bounds__(256) void pair_kernel(
    const float* __restrict__ pb,       // [F,N,4]
    const float* __restrict__ il,       // [F,N,K]
    const float* __restrict__ tb,       // [F,M,4]
    const int*   __restrict__ tids,     // [F,M]
    const int*   __restrict__ pred_idx, // [F,M]
    float* __restrict__ pair_out)       // [3, F*M]
{
    const int wave = threadIdx.x >> 6;
    const int lane = threadIdx.x & 63;
    const int pair = blockIdx.x * 4 + wave;     // 0..4095
    const int f = pair >> 5;
    const int m = pair & (M_TGT - 1);

    const int idx = pred_idx[pair];
    const float* base = il + ((size_t)f * N_PRED + idx) * K_ID;  // 2KB-aligned
    const float4* b4 = (const float4*)base;

    float4 x0 = b4[lane];
    float4 x1 = b4[64 + lane];

    float mx = fmaxf(fmaxf(fmaxf(x0.x, x0.y), fmaxf(x0.z, x0.w)),
                     fmaxf(fmaxf(x1.x, x1.y), fmaxf(x1.z, x1.w)));
#pragma unroll
    for (int off = 32; off > 0; off >>= 1) mx = fmaxf(mx, __shfl_xor(mx, off));
    float se = expf(x0.x - mx) + expf(x0.y - mx) + expf(x0.z - mx) + expf(x0.w - mx)
             + expf(x1.x - mx) + expf(x1.y - mx) + expf(x1.z - mx) + expf(x1.w - mx);
#pragma unroll
    for (int off = 32; off > 0; off >>= 1) se += __shfl_xor(se, off);
    float lse = mx + logf(se);

    if (lane == 0) {
        const float* bp = pb + ((size_t)f * N_PRED + idx) * 4;
        const float* tp = tb + ((size_t)f * M_TGT + m) * 4;
        float bcx = bp[0], bcy = bp[1], bw = bp[2], bh = bp[3];
        float tcx = tp[0], tcy = tp[1], tw = tp[2], th = tp[3];
        float l1 = fabsf(bcx - tcx) + fabsf(bcy - tcy) + fabsf(bw - tw) + fabsf(bh - th);
        float ax0 = bcx - 0.5f * bw, ay0 = bcy - 0.5f * bh;
        float ax1 = bcx + 0.5f * bw, ay1 = bcy + 0.5f * bh;
        float tx0 = tcx - 0.5f * tw, ty0 = tcy - 0.5f * th;
        float tx1 = tcx + 0.5f * tw, ty1 = tcy + 0.5f * th;
        float a1 = (ax1 - ax0) * (ay1 - ay0);
        float a2 = (tx1 - tx0) * (ty1 - ty0);
        float iw = fmaxf(fminf(ax1, tx1) - fmaxf(ax0, tx0), 0.f);
        float ih = fmaxf(fminf(ay1, ty1) - fmaxf(ay0, ty0), 0.f);
        float inter = iw * ih;
        float uni = a1 + a2 - inter;
        float iou = inter / uni;
        float cw = fmaxf(fmaxf(ax1, tx1) - fminf(ax0, tx0), 0.f);
        float ch = fmaxf(fmaxf(ay1, ty1) - fminf(ay0, ty0), 0.f);
        float ac = cw * ch;
        float giou = iou - (ac - uni) / ac;
        int tg = tids[pair];
        float nll = lse - base[tg];
        pair_out[pair]                        = l1;
        pair_out[F_FRAMES * M_TGT + pair]     = giou;
        pair_out[2 * F_FRAMES * M_TGT + pair] = nll;
    }
}

// ---------------------------------------------------------------------------
// Kernel 3: deterministic reduction of 4096x3 partials -> 5 outputs.
// ---------------------------------------------------------------------------
__global__ __launch_bounds__(256) void finalize_kernel(
    const float* __restrict__ pr, float* __restrict__ out)
{
    constexpr int P = F_FRAMES * M_TGT;   // 4096
    float s0 = 0.f, s1 = 0.f, s2 = 0.f;
    for (int i = threadIdx.x; i < P; i += 256) {
        s0 += pr[i];
        s1 += pr[P + i];
        s2 += pr[2 * P + i];
    }
#pragma unroll
    for (int off = 32; off > 0; off >>= 1) {
        s0 += __shfl_xor(s0, off);
        s1 += __shfl_xor(s1, off);
        s2 += __shfl_xor(s2, off);
    }
    __shared__ float w0[4], w1[4], w2[4];
    const int wave = threadIdx.x >> 6, lane = threadIdx.x & 63;
    if (lane == 0) { w0[wave] = s0; w1[wave] = s1; w2[wave] = s2; }
    __syncthreads();
    if (threadIdx.x == 0) {
        float S0 = w0[0] + w0[1] + w0[2] + w0[3];
        float S1 = w1[0] + w1[1] + w1[2] + w1[3];
        float S2 = w2[0] + w2[1] + w2[2] + w2[3];
        float l1  = S0 * (1.f / (P * 4));
        float gl  = 1.f - S1 * (1.f / P);
        float idl = S2 * (1.f / P);
        out[0] = 5.f * l1 + 2.f * gl + 1.f * idl;   // + 2*0 cls
        out[1] = 0.f;
        out[2] = l1;
        out[3] = gl;
        out[4] = idl;
    }
}

extern "C" void kernel_launch(void* const* d_in, const int* in_sizes, int n_in,
                              void* d_out, int out_size, void* d_ws, size_t ws_size,
                              hipStream_t stream) {
    const float* pl     = (const float*)d_in[0];   // pred_logits  [8,16,300,2]
    const float* pb     = (const float*)d_in[1];   // pred_boxes   [8,16,300,4]
    const float* il     = (const float*)d_in[2];   // id_logits    [8,16,300,512]
    const int*   labels = (const int*)d_in[3];     // target_labels [128,32]
    const float* tb     = (const float*)d_in[4];   // target_boxes  [128,32,4]
    const int*   tids   = (const int*)d_in[5];     // target_ids    [128,32]
    float* out = (float*)d_out;

    char* ws = (char*)d_ws;
    int*   pred_idx = (int*)ws;                        // 4096 ints = 16 KB
    float* pair_out = (float*)(ws + 16384);            // 3*4096 floats = 48 KB

    hungarian_kernel<<<F_FRAMES, 64, 0, stream>>>(pl, pb, labels, tb, pred_idx);
    pair_kernel<<<F_FRAMES * M_TGT / 4, 256, 0, stream>>>(pb, il, tb, tids, pred_idx, pair_out);
    finalize_kernel<<<1, 256, 0, stream>>>(pair_out, out);
}

// Round 3
// 163.258 us; speedup vs baseline: 1.3430x; 1.0381x over previous
//
#include <hip/hip_runtime.h>
#include <math.h>

// MOTIP criterion: Hungarian matching (JV with greedy dual-feasible init) + losses.
// F=128 frames, N=300 preds, M=32 targets, C=2 classes, K1=512 id classes.

constexpr int F_FRAMES = 128;
constexpr int N_PRED   = 300;
constexpr int M_TGT    = 32;
constexpr int K_ID     = 512;
constexpr int NSLOT    = 5;     // ceil(300/64) for the wave-0 solver
constexpr int PITCH    = 301;   // LDS row pitch

// ---------- 5-element register-array dynamic access (keep in VGPRs) ----------
__device__ __forceinline__ int sel5i(const int a[NSLOT], int s) {
    int r = a[0];
    r = (s == 1) ? a[1] : r;
    r = (s == 2) ? a[2] : r;
    r = (s == 3) ? a[3] : r;
    r = (s == 4) ? a[4] : r;
    return r;
}
__device__ __forceinline__ float sel5f(const float a[NSLOT], int s) {
    float r = a[0];
    r = (s == 1) ? a[1] : r;
    r = (s == 2) ? a[2] : r;
    r = (s == 3) ? a[3] : r;
    r = (s == 4) ? a[4] : r;
    return r;
}
__device__ __forceinline__ void set5i(int a[NSLOT], int s, int val) {
    if (s == 0) a[0] = val;
    if (s == 1) a[1] = val;
    if (s == 2) a[2] = val;
    if (s == 3) a[3] = val;
    if (s == 4) a[4] = val;
}
// monotone float -> uint mapping (order-preserving, handles negatives)
__device__ __forceinline__ unsigned mono32(float x) {
    unsigned b = __float_as_uint(x);
    return b ^ ((b & 0x80000000u) ? 0xFFFFFFFFu : 0x80000000u);
}

// ---------------------------------------------------------------------------
// Kernel 1: per-frame cost matrix (LDS) + Jonker-Volgenant assignment.
// One block = one frame, 256 threads (4 waves).
//  - cost fill + greedy row-min init: all 4 waves (each thread owns <=2 cols)
//  - Dijkstra cleanup for collision rows (~2/frame): wave 0 only, register
//    state + shuffles, no barriers in the loop.
// ---------------------------------------------------------------------------
__global__ __launch_bounds__(256) void hungarian_kernel(
    const float* __restrict__ pl,      // [F,N,2]
    const float* __restrict__ pb,      // [F,N,4]
    const int*   __restrict__ labels,  // [F,M]
    const float* __restrict__ tb,      // [F,M,4]
    int* __restrict__ pred_idx)        // [F,M]
{
    const int f    = blockIdx.x;
    const int tid  = threadIdx.x;
    const int lane = tid & 63;
    const int wave = tid >> 6;

    __shared__ float s_cost[M_TGT * PITCH];     // ~38.5 KB
    __shared__ int   s_claim[N_PRED];
    __shared__ float s_tgt[M_TGT][9];           // cx,cy,w,h,x0,y0,x1,y1,area
    __shared__ int   s_lab[M_TGT];
    __shared__ float s_rowval[M_TGT];
    __shared__ int   s_rowarg[M_TGT];

    if (tid < M_TGT) {
        const float4 t4 = ((const float4*)tb)[(size_t)f * M_TGT + tid];
        float cx = t4.x, cy = t4.y, w = t4.z, h = t4.w;
        s_tgt[tid][0] = cx; s_tgt[tid][1] = cy; s_tgt[tid][2] = w; s_tgt[tid][3] = h;
        float x0 = cx - 0.5f * w, y0 = cy - 0.5f * h;
        float x1 = cx + 0.5f * w, y1 = cy + 0.5f * h;
        s_tgt[tid][4] = x0; s_tgt[tid][5] = y0; s_tgt[tid][6] = x1; s_tgt[tid][7] = y1;
        s_tgt[tid][8] = (x1 - x0) * (y1 - y0);
        s_lab[tid] = labels[f * M_TGT + tid];
    }
    for (int j = tid; j < N_PRED; j += 256) s_claim[j] = 0x7fffffff;

    // ---- per-thread pred data: up to 2 columns (j = tid, tid+256) ----
    float p0[2], p1[2], pcx[2], pcy[2], pw[2], ph[2];
    float px0[2], py0[2], px1[2], py1[2], parea[2];
#pragma unroll
    for (int c = 0; c < 2; ++c) {
        int j = tid + c * 256;
        p0[c] = p1[c] = pcx[c] = pcy[c] = pw[c] = ph[c] = 0.f;
        px0[c] = py0[c] = px1[c] = py1[c] = parea[c] = 0.f;
        if (j < N_PRED) {
            float2 lg = ((const float2*)pl)[(size_t)f * N_PRED + j];
            float mx  = fmaxf(lg.x, lg.y);
            float e0  = expf(lg.x - mx), e1 = expf(lg.y - mx);
            float inv = 1.0f / (e0 + e1);
            p0[c] = e0 * inv; p1[c] = e1 * inv;
            float4 b4 = ((const float4*)pb)[(size_t)f * N_PRED + j];
            pcx[c] = b4.x; pcy[c] = b4.y; pw[c] = b4.z; ph[c] = b4.w;
            px0[c] = b4.x - 0.5f * b4.z; py0[c] = b4.y - 0.5f * b4.w;
            px1[c] = b4.x + 0.5f * b4.z; py1[c] = b4.y + 0.5f * b4.w;
            parea[c] = (px1[c] - px0[c]) * (py1[c] - py0[c]);
        }
    }
    __syncthreads();

    // ---- cost fill: C[m][j] = 2*(-prob[label]) + 5*L1 - 2*giou ----
    for (int m = 0; m < M_TGT; ++m) {
        float tcx = s_tgt[m][0], tcy = s_tgt[m][1], tw = s_tgt[m][2], th = s_tgt[m][3];
        float tx0 = s_tgt[m][4], ty0 = s_tgt[m][5], tx1 = s_tgt[m][6], ty1 = s_tgt[m][7];
        float ta  = s_tgt[m][8];
        int   lab = s_lab[m];
#pragma unroll
        for (int c = 0; c < 2; ++c) {
            int j = tid + c * 256;
            if (j < N_PRED) {
                float ccls = -((lab == 0) ? p0[c] : p1[c]);
                float cl1  = fabsf(pcx[c] - tcx) + fabsf(pcy[c] - tcy)
                           + fabsf(pw[c] - tw)  + fabsf(ph[c] - th);
                float ltx = fmaxf(px0[c], tx0), lty = fmaxf(py0[c], ty0);
                float rbx = fminf(px1[c], tx1), rby = fminf(py1[c], ty1);
                float iw = fmaxf(rbx - ltx, 0.f), ih = fmaxf(rby - lty, 0.f);
                float inter = iw * ih;
                float uni   = parea[c] + ta - inter;
                float iou   = inter / uni;
                float Ltx = fminf(px0[c], tx0), Lty = fminf(py0[c], ty0);
                float Rbx = fmaxf(px1[c], tx1), Rby = fmaxf(py1[c], ty1);
                float cw = fmaxf(Rbx - Ltx, 0.f), ch = fmaxf(Rby - Lty, 0.f);
                float ac = cw * ch;
                float giou = iou - (ac - uni) / ac;
                s_cost[m * PITCH + j] = 2.f * ccls + 5.f * cl1 - 2.f * giou;
            }
        }
    }
    __syncthreads();

    // ---- greedy init: row minima, 8 threads per row ----
    {
        int m = tid >> 3, k = tid & 7;
        float bv = INFINITY; int bj = 0;
        const float* crow = s_cost + m * PITCH;
        for (int j = k; j < N_PRED; j += 8) {
            float c = crow[j];
            if (c < bv) { bv = c; bj = j; }
        }
#pragma unroll
        for (int off = 1; off < 8; off <<= 1) {
            float ov = __shfl_xor(bv, off);
            int   oj = __shfl_xor(bj, off);
            if (ov < bv || (ov == bv && oj < bj)) { bv = ov; bj = oj; }
        }
        if (k == 0) {
            s_rowval[m] = bv;
            s_rowarg[m] = bj;
            atomicMin(&s_claim[bj], m);   // lowest row wins contested col
        }
    }
    __syncthreads();

    if (wave != 0) return;   // Dijkstra cleanup is wave-0 only

    // ---- wave-0 solver state ----
    int pcol[NSLOT];
#pragma unroll
    for (int s = 0; s < NSLOT; ++s) {
        int j = s * 64 + lane;
        pcol[s] = -1;
        if (j < N_PRED) { int c = s_claim[j]; if (c != 0x7fffffff) pcol[s] = c; }
    }
    float v[NSLOT];
#pragma unroll
    for (int s = 0; s < NSLOT; ++s) v[s] = 0.f;

    float u_reg = 0.f;
    bool assigned = false;
    if (lane < M_TGT) {
        u_reg = s_rowval[lane];
        assigned = (s_claim[s_rowarg[lane]] == lane);
    }
    unsigned freeMask = ~(unsigned)(__ballot(assigned) & 0xFFFFFFFFull);

    // ---- Dijkstra phases for unassigned rows only ----
    while (freeMask) {
        int i = __ffs(freeMask) - 1;
        freeMask &= freeMask - 1;

        float minv[NSLOT]; int way[NSLOT]; int used[NSLOT];
#pragma unroll
        for (int s = 0; s < NSLOT; ++s) { minv[s] = INFINITY; way[s] = -1; used[s] = 0; }
        unsigned treeMask = 0;
        int i0 = i, j0 = -1;

        for (int guard = 0; guard < 4096; ++guard) {
            treeMask |= 1u << i0;
            float u_i0 = __shfl(u_reg, i0);
            const float* crow2 = s_cost + i0 * PITCH;
            unsigned bkey = 0xFFFFFFFFu;
#pragma unroll
            for (int s = 0; s < NSLOT; ++s) {
                int j = s * 64 + lane;
                if (j < N_PRED && !used[s]) {
                    float cur = crow2[j] - u_i0 - v[s];
                    if (cur < minv[s]) { minv[s] = cur; way[s] = j0; }
                    unsigned key = (mono32(minv[s]) & 0xFFFFFE00u) | (unsigned)j;
                    bkey = min(bkey, key);
                }
            }
#pragma unroll
            for (int off = 32; off > 0; off >>= 1)
                bkey = min(bkey, (unsigned)__shfl_xor((int)bkey, off));
            int j1 = bkey & 0x1FF;
            int slot1 = j1 >> 6, lane1 = j1 & 63;
            float delta = __shfl(sel5f(minv, slot1), lane1);   // exact min value

            if (lane < M_TGT && ((treeMask >> lane) & 1)) u_reg += delta;
#pragma unroll
            for (int s = 0; s < NSLOT; ++s) {
                int j = s * 64 + lane;
                if (j < N_PRED) { if (used[s]) v[s] -= delta; else minv[s] -= delta; }
            }
            int pj1 = __shfl(sel5i(pcol, slot1), lane1);
            if (lane == lane1) set5i(used, slot1, 1);
            j0 = j1;
            if (pj1 < 0) break;
            i0 = pj1;
        }
        // augment along way[] chain
        int j = j0;
        while (true) {
            int slot = j >> 6, ln = j & 63;
            int wj = __shfl(sel5i(way, slot), ln);
            int newp = (wj < 0) ? i : __shfl(sel5i(pcol, wj >> 6), wj & 63);
            if (lane == ln) set5i(pcol, slot, newp);
            if (wj < 0) break;
            j = wj;
        }
    }

    // write col4row: pred_idx[f][row] = col
#pragma unroll
    for (int s = 0; s < NSLOT; ++s) {
        int j = s * 64 + lane;
        if (j < N_PRED && pcol[s] >= 0) pred_idx[f * M_TGT + pcol[s]] = j;
    }
}

// ---------------------------------------------------------------------------
// Kernel 2: per-pair losses. One wave per (f,m) pair; 4 waves/block.
// ---------------------------------------------------------------------------
__global__ __launch_bounds__(256) void pair_kernel(
    const float* __restrict__ pb,       // [F,N,4]
    const float* __restrict__ il,       // [F,N,K]
    const float* __restrict__ tb,       // [F,M,4]
    const int*   __restrict__ tids,     // [F,M]
    const int*   __restrict__ pred_idx, // [F,M]
    float* __restrict__ pair_out)       // [3, F*M]
{
    const int wave = threadIdx.x >> 6;
    const int lane = threadIdx.x & 63;
    const int pair = blockIdx.x * 4 + wave;     // 0..4095
    const int f = pair >> 5;
    const int m = pair & (M_TGT - 1);

    const int idx = pred_idx[pair];
    const float* base = il + ((size_t)f * N_PRED + idx) * K_ID;  // 2KB-aligned
    const float4* b4 = (const float4*)base;

    float4 x0 = b4[lane];
    float4 x1 = b4[64 + lane];

    float mx = fmaxf(fmaxf(fmaxf(x0.x, x0.y), fmaxf(x0.z, x0.w)),
                     fmaxf(fmaxf(x1.x, x1.y), fmaxf(x1.z, x1.w)));
#pragma unroll
    for (int off = 32; off > 0; off >>= 1) mx = fmaxf(mx, __shfl_xor(mx, off));
    float se = expf(x0.x - mx) + expf(x0.y - mx) + expf(x0.z - mx) + expf(x0.w - mx)
             + expf(x1.x - mx) + expf(x1.y - mx) + expf(x1.z - mx) + expf(x1.w - mx);
#pragma unroll
    for (int off = 32; off > 0; off >>= 1) se += __shfl_xor(se, off);
    float lse = mx + logf(se);

    if (lane == 0) {
        const float* bp = pb + ((size_t)f * N_PRED + idx) * 4;
        const float* tp = tb + ((size_t)f * M_TGT + m) * 4;
        float bcx = bp[0], bcy = bp[1], bw = bp[2], bh = bp[3];
        float tcx = tp[0], tcy = tp[1], tw = tp[2], th = tp[3];
        float l1 = fabsf(bcx - tcx) + fabsf(bcy - tcy) + fabsf(bw - tw) + fabsf(bh - th);
        float ax0 = bcx - 0.5f * bw, ay0 = bcy - 0.5f * bh;
        float ax1 = bcx + 0.5f * bw, ay1 = bcy + 0.5f * bh;
        float tx0 = tcx - 0.5f * tw, ty0 = tcy - 0.5f * th;
        float tx1 = tcx + 0.5f * tw, ty1 = tcy + 0.5f * th;
        float a1 = (ax1 - ax0) * (ay1 - ay0);
        float a2 = (tx1 - tx0) * (ty1 - ty0);
        float iw = fmaxf(fminf(ax1, tx1) - fmaxf(ax0, tx0), 0.f);
        float ih = fmaxf(fminf(ay1, ty1) - fmaxf(ay0, ty0), 0.f);
        float inter = iw * ih;
        float uni = a1 + a2 - inter;
        float iou = inter / uni;
        float cw = fmaxf(fmaxf(ax1, tx1) - fminf(ax0, tx0), 0.f);
        float ch = fmaxf(fmaxf(ay1, ty1) - fminf(ay0, ty0), 0.f);
        float ac = cw * ch;
        float giou = iou - (ac - uni) / ac;
        int tg = tids[pair];
        float nll = lse - base[tg];
        pair_out[pair]                        = l1;
        pair_out[F_FRAMES * M_TGT + pair]     = giou;
        pair_out[2 * F_FRAMES * M_TGT + pair] = nll;
    }
}

// ---------------------------------------------------------------------------
// Kernel 3: deterministic reduction of 4096x3 partials -> 5 outputs.
// ---------------------------------------------------------------------------
__global__ __launch_bounds__(256) void finalize_kernel(
    const float* __restrict__ pr, float* __restrict__ out)
{
    constexpr int P = F_FRAMES * M_TGT;   // 4096
    float s0 = 0.f, s1 = 0.f, s2 = 0.f;
    for (int i = threadIdx.x; i < P; i += 256) {
        s0 += pr[i];
        s1 += pr[P + i];
        s2 += pr[2 * P + i];
    }
#pragma unroll
    for (int off = 32; off > 0; off >>= 1) {
        s0 += __shfl_xor(s0, off);
        s1 += __shfl_xor(s1, off);
        s2 += __shfl_xor(s2, off);
    }
    __shared__ float w0[4], w1[4], w2[4];
    const int wave = threadIdx.x >> 6, lane = threadIdx.x & 63;
    if (lane == 0) { w0[wave] = s0; w1[wave] = s1; w2[wave] = s2; }
    __syncthreads();
    if (threadIdx.x == 0) {
        float S0 = w0[0] + w0[1] + w0[2] + w0[3];
        float S1 = w1[0] + w1[1] + w1[2] + w1[3];
        float S2 = w2[0] + w2[1] + w2[2] + w2[3];
        float l1  = S0 * (1.f / (P * 4));
        float gl  = 1.f - S1 * (1.f / P);
        float idl = S2 * (1.f / P);
        out[0] = 5.f * l1 + 2.f * gl + 1.f * idl;   // + 2*0 cls
        out[1] = 0.f;
        out[2] = l1;
        out[3] = gl;
        out[4] = idl;
    }
}

extern "C" void kernel_launch(void* const* d_in, const int* in_sizes, int n_in,
                              void* d_out, int out_size, void* d_ws, size_t ws_size,
                              hipStream_t stream) {
    const float* pl     = (const float*)d_in[0];   // pred_logits  [8,16,300,2]
    const float* pb     = (const float*)d_in[1];   // pred_boxes   [8,16,300,4]
    const float* il     = (const float*)d_in[2];   // id_logits    [8,16,300,512]
    const int*   labels = (const int*)d_in[3];     // target_labels [128,32]
    const float* tb     = (const float*)d_in[4];   // target_boxes  [128,32,4]
    const int*   tids   = (const int*)d_in[5];     // target_ids    [128,32]
    float* out = (float*)d_out;

    char* ws = (char*)d_ws;
    int*   pred_idx = (int*)ws;                        // 4096 ints = 16 KB
    float* pair_out = (float*)(ws + 16384);            // 3*4096 floats = 48 KB

    hungarian_kernel<<<F_FRAMES, 256, 0, stream>>>(pl, pb, labels, tb, pred_idx);
    pair_kernel<<<F_FRAMES * M_TGT / 4, 256, 0, stream>>>(pb, il, tb, tids, pred_idx, pair_out);
    finalize_kernel<<<1, 256, 0, stream>>>(pair_out, out);
}

// Round 4
// 158.772 us; speedup vs baseline: 1.3809x; 1.0283x over previous
//
#include <hip/hip_runtime.h>
#include <math.h>

// MOTIP criterion, fused: per-frame cost + JV Hungarian + pair losses in ONE
// kernel (one block per frame), then a tiny 1-block finalize.
// F=128 frames, N=300 preds, M=32 targets, C=2 classes, K1=512 id classes.

constexpr int F_FRAMES = 128;
constexpr int N_PRED   = 300;
constexpr int M_TGT    = 32;
constexpr int K_ID     = 512;
constexpr int NSLOT    = 5;     // ceil(300/64) for the wave-0 solver
constexpr int PITCH    = 301;   // LDS row pitch

// ---------- 5-element register-array dynamic access ----------
__device__ __forceinline__ int sel5i(const int a[NSLOT], int s) {
    int r = a[0];
    r = (s == 1) ? a[1] : r;
    r = (s == 2) ? a[2] : r;
    r = (s == 3) ? a[3] : r;
    r = (s == 4) ? a[4] : r;
    return r;
}
__device__ __forceinline__ float sel5f(const float a[NSLOT], int s) {
    float r = a[0];
    r = (s == 1) ? a[1] : r;
    r = (s == 2) ? a[2] : r;
    r = (s == 3) ? a[3] : r;
    r = (s == 4) ? a[4] : r;
    return r;
}
__device__ __forceinline__ void set5i(int a[NSLOT], int s, int val) {
    if (s == 0) a[0] = val;
    if (s == 1) a[1] = val;
    if (s == 2) a[2] = val;
    if (s == 3) a[3] = val;
    if (s == 4) a[4] = val;
}
// monotone float -> uint (order-preserving)
__device__ __forceinline__ unsigned mono32(float x) {
    unsigned b = __float_as_uint(x);
    return b ^ ((b & 0x80000000u) ? 0xFFFFFFFFu : 0x80000000u);
}

// ---------------------------------------------------------------------------
// Fused kernel: one block (256 thr) per frame.
//   A: load preds/targets, cost fill, greedy row-min init  (all 4 waves)
//   B: Dijkstra cleanup for collision rows                  (wave 0 only)
//   C: pair losses (8 threads/pair), per-frame partial sums (all 4 waves)
// Writes frame_part[f] = {sum_l1, sum_giou, sum_nll}.
// ---------------------------------------------------------------------------
__global__ __launch_bounds__(256) void motip_fused_kernel(
    const float* __restrict__ pl,      // [F,N,2]
    const float* __restrict__ pb,      // [F,N,4]
    const float* __restrict__ il,      // [F,N,K]
    const int*   __restrict__ labels,  // [F,M]
    const float* __restrict__ tb,      // [F,M,4]
    const int*   __restrict__ tids,    // [F,M]
    float* __restrict__ frame_part)    // [F,4]
{
    const int f    = blockIdx.x;
    const int tid  = threadIdx.x;
    const int lane = tid & 63;
    const int wave = tid >> 6;

    __shared__ float s_cost[M_TGT * PITCH];     // 38528 B
    __shared__ float s_pbox[N_PRED][4];         // pred cxcywh (4800 B)
    __shared__ int   s_claim[N_PRED];
    __shared__ float s_tgt[M_TGT][9];           // cx,cy,w,h,x0,y0,x1,y1,area
    __shared__ int   s_lab[M_TGT];
    __shared__ float s_rowval[M_TGT];
    __shared__ int   s_rowarg[M_TGT];
    __shared__ int   s_col4row[M_TGT];
    __shared__ float s_pl1[M_TGT], s_pgi[M_TGT], s_pnl[M_TGT];

    // ---- stage A: targets ----
    if (tid < M_TGT) {
        const float4 t4 = ((const float4*)tb)[(size_t)f * M_TGT + tid];
        float cx = t4.x, cy = t4.y, w = t4.z, h = t4.w;
        s_tgt[tid][0] = cx; s_tgt[tid][1] = cy; s_tgt[tid][2] = w; s_tgt[tid][3] = h;
        float x0 = cx - 0.5f * w, y0 = cy - 0.5f * h;
        float x1 = cx + 0.5f * w, y1 = cy + 0.5f * h;
        s_tgt[tid][4] = x0; s_tgt[tid][5] = y0; s_tgt[tid][6] = x1; s_tgt[tid][7] = y1;
        s_tgt[tid][8] = (x1 - x0) * (y1 - y0);
        s_lab[tid] = labels[f * M_TGT + tid];
    }
    for (int j = tid; j < N_PRED; j += 256) s_claim[j] = 0x7fffffff;

    // per-thread pred data: up to 2 columns (j = tid, tid+256)
    float p0[2], p1[2], pcx[2], pcy[2], pw[2], ph[2];
    float px0[2], py0[2], px1[2], py1[2], parea[2];
#pragma unroll
    for (int c = 0; c < 2; ++c) {
        int j = tid + c * 256;
        p0[c] = p1[c] = pcx[c] = pcy[c] = pw[c] = ph[c] = 0.f;
        px0[c] = py0[c] = px1[c] = py1[c] = parea[c] = 0.f;
        if (j < N_PRED) {
            float2 lg = ((const float2*)pl)[(size_t)f * N_PRED + j];
            float mx  = fmaxf(lg.x, lg.y);
            float e0  = expf(lg.x - mx), e1 = expf(lg.y - mx);
            float inv = 1.0f / (e0 + e1);
            p0[c] = e0 * inv; p1[c] = e1 * inv;
            float4 b4 = ((const float4*)pb)[(size_t)f * N_PRED + j];
            pcx[c] = b4.x; pcy[c] = b4.y; pw[c] = b4.z; ph[c] = b4.w;
            s_pbox[j][0] = b4.x; s_pbox[j][1] = b4.y; s_pbox[j][2] = b4.z; s_pbox[j][3] = b4.w;
            px0[c] = b4.x - 0.5f * b4.z; py0[c] = b4.y - 0.5f * b4.w;
            px1[c] = b4.x + 0.5f * b4.z; py1[c] = b4.y + 0.5f * b4.w;
            parea[c] = (px1[c] - px0[c]) * (py1[c] - py0[c]);
        }
    }
    __syncthreads();

    // cost fill: C[m][j] = 2*(-prob[label]) + 5*L1 - 2*giou
    for (int m = 0; m < M_TGT; ++m) {
        float tcx = s_tgt[m][0], tcy = s_tgt[m][1], tw = s_tgt[m][2], th = s_tgt[m][3];
        float tx0 = s_tgt[m][4], ty0 = s_tgt[m][5], tx1 = s_tgt[m][6], ty1 = s_tgt[m][7];
        float ta  = s_tgt[m][8];
        int   lab = s_lab[m];
#pragma unroll
        for (int c = 0; c < 2; ++c) {
            int j = tid + c * 256;
            if (j < N_PRED) {
                float ccls = -((lab == 0) ? p0[c] : p1[c]);
                float cl1  = fabsf(pcx[c] - tcx) + fabsf(pcy[c] - tcy)
                           + fabsf(pw[c] - tw)  + fabsf(ph[c] - th);
                float ltx = fmaxf(px0[c], tx0), lty = fmaxf(py0[c], ty0);
                float rbx = fminf(px1[c], tx1), rby = fminf(py1[c], ty1);
                float iw = fmaxf(rbx - ltx, 0.f), ih = fmaxf(rby - lty, 0.f);
                float inter = iw * ih;
                float uni   = parea[c] + ta - inter;
                float iou   = inter / uni;
                float Ltx = fminf(px0[c], tx0), Lty = fminf(py0[c], ty0);
                float Rbx = fmaxf(px1[c], tx1), Rby = fmaxf(py1[c], ty1);
                float cw = fmaxf(Rbx - Ltx, 0.f), ch = fmaxf(Rby - Lty, 0.f);
                float ac = cw * ch;
                float giou = iou - (ac - uni) / ac;
                s_cost[m * PITCH + j] = 2.f * ccls + 5.f * cl1 - 2.f * giou;
            }
        }
    }
    __syncthreads();

    // greedy init: row minima, 8 threads per row
    {
        int m = tid >> 3, k = tid & 7;
        float bv = INFINITY; int bj = 0;
        const float* crow = s_cost + m * PITCH;
        for (int j = k; j < N_PRED; j += 8) {
            float c = crow[j];
            if (c < bv) { bv = c; bj = j; }
        }
#pragma unroll
        for (int off = 1; off < 8; off <<= 1) {
            float ov = __shfl_xor(bv, off);
            int   oj = __shfl_xor(bj, off);
            if (ov < bv || (ov == bv && oj < bj)) { bv = ov; bj = oj; }
        }
        if (k == 0) {
            s_rowval[m] = bv;
            s_rowarg[m] = bj;
            atomicMin(&s_claim[bj], m);   // lowest row wins contested col
        }
    }
    __syncthreads();

    // ---- stage B: Dijkstra cleanup, wave 0 only ----
    if (wave == 0) {
        int pcol[NSLOT];
#pragma unroll
        for (int s = 0; s < NSLOT; ++s) {
            int j = s * 64 + lane;
            pcol[s] = -1;
            if (j < N_PRED) { int c = s_claim[j]; if (c != 0x7fffffff) pcol[s] = c; }
        }
        float v[NSLOT];
#pragma unroll
        for (int s = 0; s < NSLOT; ++s) v[s] = 0.f;

        float u_reg = 0.f;
        bool assigned = false;
        if (lane < M_TGT) {
            u_reg = s_rowval[lane];
            assigned = (s_claim[s_rowarg[lane]] == lane);
        }
        unsigned freeMask = ~(unsigned)(__ballot(assigned) & 0xFFFFFFFFull);

        while (freeMask) {
            int i = __ffs(freeMask) - 1;
            freeMask &= freeMask - 1;

            float minv[NSLOT]; int way[NSLOT]; int used[NSLOT];
#pragma unroll
            for (int s = 0; s < NSLOT; ++s) { minv[s] = INFINITY; way[s] = -1; used[s] = 0; }
            unsigned treeMask = 0;
            int i0 = i, j0 = -1;

            for (int guard = 0; guard < 4096; ++guard) {
                treeMask |= 1u << i0;
                float u_i0 = __shfl(u_reg, i0);
                const float* crow2 = s_cost + i0 * PITCH;
                unsigned bkey = 0xFFFFFFFFu;
#pragma unroll
                for (int s = 0; s < NSLOT; ++s) {
                    int j = s * 64 + lane;
                    if (j < N_PRED && !used[s]) {
                        float cur = crow2[j] - u_i0 - v[s];
                        if (cur < minv[s]) { minv[s] = cur; way[s] = j0; }
                        unsigned key = (mono32(minv[s]) & 0xFFFFFE00u) | (unsigned)j;
                        bkey = min(bkey, key);
                    }
                }
#pragma unroll
                for (int off = 32; off > 0; off >>= 1)
                    bkey = min(bkey, (unsigned)__shfl_xor((int)bkey, off));
                int j1 = bkey & 0x1FF;
                int slot1 = j1 >> 6, lane1 = j1 & 63;
                float delta = __shfl(sel5f(minv, slot1), lane1);

                if (lane < M_TGT && ((treeMask >> lane) & 1)) u_reg += delta;
#pragma unroll
                for (int s = 0; s < NSLOT; ++s) {
                    int j = s * 64 + lane;
                    if (j < N_PRED) { if (used[s]) v[s] -= delta; else minv[s] -= delta; }
                }
                int pj1 = __shfl(sel5i(pcol, slot1), lane1);
                if (lane == lane1) set5i(used, slot1, 1);
                j0 = j1;
                if (pj1 < 0) break;
                i0 = pj1;
            }
            // augment
            int j = j0;
            while (true) {
                int slot = j >> 6, ln = j & 63;
                int wj = __shfl(sel5i(way, slot), ln);
                int newp = (wj < 0) ? i : __shfl(sel5i(pcol, wj >> 6), wj & 63);
                if (lane == ln) set5i(pcol, slot, newp);
                if (wj < 0) break;
                j = wj;
            }
        }

        // row -> col into LDS
#pragma unroll
        for (int s = 0; s < NSLOT; ++s) {
            int j = s * 64 + lane;
            if (j < N_PRED && pcol[s] >= 0) s_col4row[pcol[s]] = j;
        }
    }
    __syncthreads();

    // ---- stage C: pair losses, 8 threads per pair ----
    {
        const int m = tid >> 3, k = tid & 7;
        const int idx = s_col4row[m];
        const float* base = il + ((size_t)f * N_PRED + idx) * K_ID;
        const float4* b4 = (const float4*)base + k * 16;

        // half 1: 32 floats
        float4 c0[8];
#pragma unroll
        for (int t = 0; t < 8; ++t) c0[t] = b4[t];
        float m1 = -INFINITY;
#pragma unroll
        for (int t = 0; t < 8; ++t)
            m1 = fmaxf(m1, fmaxf(fmaxf(c0[t].x, c0[t].y), fmaxf(c0[t].z, c0[t].w)));
        float s1 = 0.f;
#pragma unroll
        for (int t = 0; t < 8; ++t)
            s1 += expf(c0[t].x - m1) + expf(c0[t].y - m1) + expf(c0[t].z - m1) + expf(c0[t].w - m1);
        // half 2
#pragma unroll
        for (int t = 0; t < 8; ++t) c0[t] = b4[8 + t];
        float m2 = -INFINITY;
#pragma unroll
        for (int t = 0; t < 8; ++t)
            m2 = fmaxf(m2, fmaxf(fmaxf(c0[t].x, c0[t].y), fmaxf(c0[t].z, c0[t].w)));
        float s2 = 0.f;
#pragma unroll
        for (int t = 0; t < 8; ++t)
            s2 += expf(c0[t].x - m2) + expf(c0[t].y - m2) + expf(c0[t].z - m2) + expf(c0[t].w - m2);
        float M = fmaxf(m1, m2);
        float S = s1 * expf(m1 - M) + s2 * expf(m2 - M);

        // reduce across the 8 lanes of this pair
#pragma unroll
        for (int off = 1; off < 8; off <<= 1) {
            float oM = __shfl_xor(M, off);
            float oS = __shfl_xor(S, off);
            float Mn = fmaxf(M, oM);
            S = S * expf(M - Mn) + oS * expf(oM - Mn);
            M = Mn;
        }
        if (k == 0) {
            float lse = M + logf(S);
            int   tg  = tids[f * M_TGT + m];
            float nll = lse - base[tg];

            float bcx = s_pbox[idx][0], bcy = s_pbox[idx][1];
            float bw  = s_pbox[idx][2], bh  = s_pbox[idx][3];
            float tcx = s_tgt[m][0], tcy = s_tgt[m][1], tw = s_tgt[m][2], th = s_tgt[m][3];
            float l1 = fabsf(bcx - tcx) + fabsf(bcy - tcy) + fabsf(bw - tw) + fabsf(bh - th);
            float ax0 = bcx - 0.5f * bw, ay0 = bcy - 0.5f * bh;
            float ax1 = bcx + 0.5f * bw, ay1 = bcy + 0.5f * bh;
            float tx0 = s_tgt[m][4], ty0 = s_tgt[m][5], tx1 = s_tgt[m][6], ty1 = s_tgt[m][7];
            float a1 = (ax1 - ax0) * (ay1 - ay0);
            float a2 = s_tgt[m][8];
            float iw = fmaxf(fminf(ax1, tx1) - fmaxf(ax0, tx0), 0.f);
            float ih = fmaxf(fminf(ay1, ty1) - fmaxf(ay0, ty0), 0.f);
            float inter = iw * ih;
            float uni = a1 + a2 - inter;
            float iou = inter / uni;
            float cw = fmaxf(fmaxf(ax1, tx1) - fminf(ax0, tx0), 0.f);
            float ch = fmaxf(fmaxf(ay1, ty1) - fminf(ay0, ty0), 0.f);
            float ac = cw * ch;
            float giou = iou - (ac - uni) / ac;

            s_pl1[m] = l1; s_pgi[m] = giou; s_pnl[m] = nll;
        }
    }
    __syncthreads();

    // per-frame reduction of 32 pair values (wave 0)
    if (wave == 0) {
        float a = 0.f, b = 0.f, c = 0.f;
        if (lane < M_TGT) { a = s_pl1[lane]; b = s_pgi[lane]; c = s_pnl[lane]; }
#pragma unroll
        for (int off = 32; off > 0; off >>= 1) {
            a += __shfl_xor(a, off);
            b += __shfl_xor(b, off);
            c += __shfl_xor(c, off);
        }
        if (lane == 0) {
            frame_part[f * 4 + 0] = a;
            frame_part[f * 4 + 1] = b;
            frame_part[f * 4 + 2] = c;
        }
    }
}

// ---------------------------------------------------------------------------
// Finalize: 1 block, reduce 128 frame partials -> 5 outputs.
// ---------------------------------------------------------------------------
__global__ __launch_bounds__(128) void finalize_kernel(
    const float* __restrict__ fp, float* __restrict__ out)
{
    const int lane = threadIdx.x & 63;
    const int wave = threadIdx.x >> 6;
    float a = fp[threadIdx.x * 4 + 0];
    float b = fp[threadIdx.x * 4 + 1];
    float c = fp[threadIdx.x * 4 + 2];
#pragma unroll
    for (int off = 32; off > 0; off >>= 1) {
        a += __shfl_xor(a, off);
        b += __shfl_xor(b, off);
        c += __shfl_xor(c, off);
    }
    __shared__ float w[3][2];
    if (lane == 0) { w[0][wave] = a; w[1][wave] = b; w[2][wave] = c; }
    __syncthreads();
    if (threadIdx.x == 0) {
        constexpr float P = (float)(F_FRAMES * M_TGT);
        float S0 = w[0][0] + w[0][1];
        float S1 = w[1][0] + w[1][1];
        float S2 = w[2][0] + w[2][1];
        float l1  = S0 / (P * 4.f);
        float gl  = 1.f - S1 / P;
        float idl = S2 / P;
        out[0] = 5.f * l1 + 2.f * gl + 1.f * idl;   // + 2*0 cls
        out[1] = 0.f;
        out[2] = l1;
        out[3] = gl;
        out[4] = idl;
    }
}

extern "C" void kernel_launch(void* const* d_in, const int* in_sizes, int n_in,
                              void* d_out, int out_size, void* d_ws, size_t ws_size,
                              hipStream_t stream) {
    const float* pl     = (const float*)d_in[0];   // pred_logits  [8,16,300,2]
    const float* pb     = (const float*)d_in[1];   // pred_boxes   [8,16,300,4]
    const float* il     = (const float*)d_in[2];   // id_logits    [8,16,300,512]
    const int*   labels = (const int*)d_in[3];     // target_labels [128,32]
    const float* tb     = (const float*)d_in[4];   // target_boxes  [128,32,4]
    const int*   tids   = (const int*)d_in[5];     // target_ids    [128,32]
    float* out = (float*)d_out;

    float* frame_part = (float*)d_ws;              // [128,4] = 2 KB

    motip_fused_kernel<<<F_FRAMES, 256, 0, stream>>>(pl, pb, il, labels, tb, tids, frame_part);
    finalize_kernel<<<1, 128, 0, stream>>>(frame_part, out);
}

// Round 5
// 157.790 us; speedup vs baseline: 1.3895x; 1.0062x over previous
//
#include <hip/hip_runtime.h>
#include <math.h>

// MOTIP criterion, single fused kernel: cost + JV Hungarian + speculative pair
// losses overlapped with the solve + last-block global reduction.
// F=128 frames, N=300 preds, M=32 targets, C=2 classes, K1=512 id classes.

constexpr int F_FRAMES = 128;
constexpr int N_PRED   = 300;
constexpr int M_TGT    = 32;
constexpr int K_ID     = 512;
constexpr int NSLOT    = 5;     // ceil(300/64) for the wave-0 solver
constexpr int PITCH    = 301;   // LDS row pitch

// ---------- 5-element register-array dynamic access ----------
__device__ __forceinline__ int sel5i(const int a[NSLOT], int s) {
    int r = a[0];
    r = (s == 1) ? a[1] : r;
    r = (s == 2) ? a[2] : r;
    r = (s == 3) ? a[3] : r;
    r = (s == 4) ? a[4] : r;
    return r;
}
__device__ __forceinline__ float sel5f(const float a[NSLOT], int s) {
    float r = a[0];
    r = (s == 1) ? a[1] : r;
    r = (s == 2) ? a[2] : r;
    r = (s == 3) ? a[3] : r;
    r = (s == 4) ? a[4] : r;
    return r;
}
__device__ __forceinline__ void set5i(int a[NSLOT], int s, int val) {
    if (s == 0) a[0] = val;
    if (s == 1) a[1] = val;
    if (s == 2) a[2] = val;
    if (s == 3) a[3] = val;
    if (s == 4) a[4] = val;
}
// monotone float -> uint (order-preserving)
__device__ __forceinline__ unsigned mono32(float x) {
    unsigned b = __float_as_uint(x);
    return b ^ ((b & 0x80000000u) ? 0xFFFFFFFFu : 0x80000000u);
}

// ---------------------------------------------------------------------------
// Fused kernel, one block (256 thr) per frame:
//   A: load preds/targets, cost fill, greedy row-min init      (all waves)
//   B: wave 0 -> Dijkstra cleanup | waves 1-3 -> speculative
//      logsumexp for greedy-claimed columns                    (overlapped)
//   C: pair losses (reuse spec LSE; recompute changed rows), frame partials
//   D: release-store partials; last block reduces all frames -> d_out
// ---------------------------------------------------------------------------
__global__ __launch_bounds__(256) void motip_fused_kernel(
    const float* __restrict__ pl,      // [F,N,2]
    const float* __restrict__ pb,      // [F,N,4]
    const float* __restrict__ il,      // [F,N,K]
    const int*   __restrict__ labels,  // [F,M]
    const float* __restrict__ tb,      // [F,M,4]
    const int*   __restrict__ tids,    // [F,M]
    float* __restrict__ frame_part,    // [F,4] in ws
    int*   __restrict__ counter,       // zeroed by memsetAsync
    float* __restrict__ out)           // [5]
{
    const int f    = blockIdx.x;
    const int tid  = threadIdx.x;
    const int lane = tid & 63;
    const int wave = tid >> 6;

    __shared__ float s_cost[M_TGT * PITCH];     // 38528 B
    __shared__ float s_pbox[N_PRED][4];         // pred cxcywh
    __shared__ int   s_claim[N_PRED];
    __shared__ float s_tgt[M_TGT][9];           // cx,cy,w,h,x0,y0,x1,y1,area
    __shared__ int   s_lab[M_TGT];
    __shared__ int   s_tid[M_TGT];
    __shared__ float s_rowval[M_TGT];
    __shared__ int   s_rowarg[M_TGT];
    __shared__ int   s_col4row[M_TGT];
    __shared__ float s_lse[M_TGT];              // speculative LSE per row
    __shared__ float s_tgval[M_TGT];            // speculative base[tg]
    __shared__ float s_pl1[M_TGT], s_pgi[M_TGT], s_pnl[M_TGT];
    __shared__ int   s_islast;

    // ---- stage A ----
    if (tid < M_TGT) {
        const float4 t4 = ((const float4*)tb)[(size_t)f * M_TGT + tid];
        float cx = t4.x, cy = t4.y, w = t4.z, h = t4.w;
        s_tgt[tid][0] = cx; s_tgt[tid][1] = cy; s_tgt[tid][2] = w; s_tgt[tid][3] = h;
        float x0 = cx - 0.5f * w, y0 = cy - 0.5f * h;
        float x1 = cx + 0.5f * w, y1 = cy + 0.5f * h;
        s_tgt[tid][4] = x0; s_tgt[tid][5] = y0; s_tgt[tid][6] = x1; s_tgt[tid][7] = y1;
        s_tgt[tid][8] = (x1 - x0) * (y1 - y0);
        s_lab[tid] = labels[f * M_TGT + tid];
        s_tid[tid] = tids[f * M_TGT + tid];
    }
    for (int j = tid; j < N_PRED; j += 256) s_claim[j] = 0x7fffffff;

    float p0[2], p1[2], pcx[2], pcy[2], pw[2], ph[2];
    float px0[2], py0[2], px1[2], py1[2], parea[2];
#pragma unroll
    for (int c = 0; c < 2; ++c) {
        int j = tid + c * 256;
        p0[c] = p1[c] = pcx[c] = pcy[c] = pw[c] = ph[c] = 0.f;
        px0[c] = py0[c] = px1[c] = py1[c] = parea[c] = 0.f;
        if (j < N_PRED) {
            float2 lg = ((const float2*)pl)[(size_t)f * N_PRED + j];
            float mx  = fmaxf(lg.x, lg.y);
            float e0  = expf(lg.x - mx), e1 = expf(lg.y - mx);
            float inv = 1.0f / (e0 + e1);
            p0[c] = e0 * inv; p1[c] = e1 * inv;
            float4 b4 = ((const float4*)pb)[(size_t)f * N_PRED + j];
            pcx[c] = b4.x; pcy[c] = b4.y; pw[c] = b4.z; ph[c] = b4.w;
            s_pbox[j][0] = b4.x; s_pbox[j][1] = b4.y; s_pbox[j][2] = b4.z; s_pbox[j][3] = b4.w;
            px0[c] = b4.x - 0.5f * b4.z; py0[c] = b4.y - 0.5f * b4.w;
            px1[c] = b4.x + 0.5f * b4.z; py1[c] = b4.y + 0.5f * b4.w;
            parea[c] = (px1[c] - px0[c]) * (py1[c] - py0[c]);
        }
    }
    __syncthreads();

    // cost fill: C[m][j] = 2*(-prob[label]) + 5*L1 - 2*giou
    for (int m = 0; m < M_TGT; ++m) {
        float tcx = s_tgt[m][0], tcy = s_tgt[m][1], tw = s_tgt[m][2], th = s_tgt[m][3];
        float tx0 = s_tgt[m][4], ty0 = s_tgt[m][5], tx1 = s_tgt[m][6], ty1 = s_tgt[m][7];
        float ta  = s_tgt[m][8];
        int   lab = s_lab[m];
#pragma unroll
        for (int c = 0; c < 2; ++c) {
            int j = tid + c * 256;
            if (j < N_PRED) {
                float ccls = -((lab == 0) ? p0[c] : p1[c]);
                float cl1  = fabsf(pcx[c] - tcx) + fabsf(pcy[c] - tcy)
                           + fabsf(pw[c] - tw)  + fabsf(ph[c] - th);
                float ltx = fmaxf(px0[c], tx0), lty = fmaxf(py0[c], ty0);
                float rbx = fminf(px1[c], tx1), rby = fminf(py1[c], ty1);
                float iw = fmaxf(rbx - ltx, 0.f), ih = fmaxf(rby - lty, 0.f);
                float inter = iw * ih;
                float uni   = parea[c] + ta - inter;
                float iou   = inter / uni;
                float Ltx = fminf(px0[c], tx0), Lty = fminf(py0[c], ty0);
                float Rbx = fmaxf(px1[c], tx1), Rby = fmaxf(py1[c], ty1);
                float cw = fmaxf(Rbx - Ltx, 0.f), ch = fmaxf(Rby - Lty, 0.f);
                float ac = cw * ch;
                float giou = iou - (ac - uni) / ac;
                s_cost[m * PITCH + j] = 2.f * ccls + 5.f * cl1 - 2.f * giou;
            }
        }
    }
    __syncthreads();

    // greedy init: row minima, 8 threads per row
    {
        int m = tid >> 3, k = tid & 7;
        float bv = INFINITY; int bj = 0;
        const float* crow = s_cost + m * PITCH;
        for (int j = k; j < N_PRED; j += 8) {
            float c = crow[j];
            if (c < bv) { bv = c; bj = j; }
        }
#pragma unroll
        for (int off = 1; off < 8; off <<= 1) {
            float ov = __shfl_xor(bv, off);
            int   oj = __shfl_xor(bj, off);
            if (ov < bv || (ov == bv && oj < bj)) { bv = ov; bj = oj; }
        }
        if (k == 0) {
            s_rowval[m] = bv;
            s_rowarg[m] = bj;
            atomicMin(&s_claim[bj], m);
        }
    }
    __syncthreads();

    // ---- stage B: overlapped solve (wave 0) & speculative LSE (waves 1-3) ----
    if (wave == 0) {
        int pcol[NSLOT];
#pragma unroll
        for (int s = 0; s < NSLOT; ++s) {
            int j = s * 64 + lane;
            pcol[s] = -1;
            if (j < N_PRED) { int c = s_claim[j]; if (c != 0x7fffffff) pcol[s] = c; }
        }
        float v[NSLOT];
#pragma unroll
        for (int s = 0; s < NSLOT; ++s) v[s] = 0.f;

        float u_reg = 0.f;
        bool assigned = false;
        if (lane < M_TGT) {
            u_reg = s_rowval[lane];
            assigned = (s_claim[s_rowarg[lane]] == lane);
        }
        unsigned freeMask = ~(unsigned)(__ballot(assigned) & 0xFFFFFFFFull);

        while (freeMask) {
            int i = __ffs(freeMask) - 1;
            freeMask &= freeMask - 1;

            float minv[NSLOT]; int way[NSLOT]; int used[NSLOT];
#pragma unroll
            for (int s = 0; s < NSLOT; ++s) { minv[s] = INFINITY; way[s] = -1; used[s] = 0; }
            unsigned treeMask = 0;
            int i0 = i, j0 = -1;

            for (int guard = 0; guard < 4096; ++guard) {
                treeMask |= 1u << i0;
                float u_i0 = __shfl(u_reg, i0);
                const float* crow2 = s_cost + i0 * PITCH;
                unsigned bkey = 0xFFFFFFFFu;
#pragma unroll
                for (int s = 0; s < NSLOT; ++s) {
                    int j = s * 64 + lane;
                    if (j < N_PRED && !used[s]) {
                        float cur = crow2[j] - u_i0 - v[s];
                        if (cur < minv[s]) { minv[s] = cur; way[s] = j0; }
                        unsigned key = (mono32(minv[s]) & 0xFFFFFE00u) | (unsigned)j;
                        bkey = min(bkey, key);
                    }
                }
#pragma unroll
                for (int off = 32; off > 0; off >>= 1)
                    bkey = min(bkey, (unsigned)__shfl_xor((int)bkey, off));
                int j1 = bkey & 0x1FF;
                int slot1 = j1 >> 6, lane1 = j1 & 63;
                float delta = __shfl(sel5f(minv, slot1), lane1);

                if (lane < M_TGT && ((treeMask >> lane) & 1)) u_reg += delta;
#pragma unroll
                for (int s = 0; s < NSLOT; ++s) {
                    int j = s * 64 + lane;
                    if (j < N_PRED) { if (used[s]) v[s] -= delta; else minv[s] -= delta; }
                }
                int pj1 = __shfl(sel5i(pcol, slot1), lane1);
                if (lane == lane1) set5i(used, slot1, 1);
                j0 = j1;
                if (pj1 < 0) break;
                i0 = pj1;
            }
            int j = j0;
            while (true) {
                int slot = j >> 6, ln = j & 63;
                int wj = __shfl(sel5i(way, slot), ln);
                int newp = (wj < 0) ? i : __shfl(sel5i(pcol, wj >> 6), wj & 63);
                if (lane == ln) set5i(pcol, slot, newp);
                if (wj < 0) break;
                j = wj;
            }
        }
#pragma unroll
        for (int s = 0; s < NSLOT; ++s) {
            int j = s * 64 + lane;
            if (j < N_PRED && pcol[s] >= 0) s_col4row[pcol[s]] = j;
        }
    } else {
        // waves 1-3: speculative LSE for each row's greedy-claimed column
        for (int m = wave - 1; m < M_TGT; m += 3) {
            int col = s_rowarg[m];
            const float* base = il + ((size_t)f * N_PRED + col) * K_ID;
            const float4* b4 = (const float4*)base;
            float4 x0 = b4[lane];
            float4 x1 = b4[64 + lane];
            float mx = fmaxf(fmaxf(fmaxf(x0.x, x0.y), fmaxf(x0.z, x0.w)),
                             fmaxf(fmaxf(x1.x, x1.y), fmaxf(x1.z, x1.w)));
#pragma unroll
            for (int off = 32; off > 0; off >>= 1) mx = fmaxf(mx, __shfl_xor(mx, off));
            float se = expf(x0.x - mx) + expf(x0.y - mx) + expf(x0.z - mx) + expf(x0.w - mx)
                     + expf(x1.x - mx) + expf(x1.y - mx) + expf(x1.z - mx) + expf(x1.w - mx);
#pragma unroll
            for (int off = 32; off > 0; off >>= 1) se += __shfl_xor(se, off);
            if (lane == 0) {
                s_lse[m]   = mx + logf(se);
                s_tgval[m] = base[s_tid[m]];
            }
        }
    }
    __syncthreads();

    // ---- stage C: pair losses (8 threads/pair), reuse speculative LSE ----
    {
        const int m = tid >> 3, k = tid & 7;
        const int idx = s_col4row[m];
        const bool match = (idx == s_rowarg[m]);
        float lse = s_lse[m], tgval = s_tgval[m];

        if (!match) {   // recompute LSE for changed rows (~2/frame)
            const float* base = il + ((size_t)f * N_PRED + idx) * K_ID;
            const float4* b4 = (const float4*)base + k * 16;
            float4 c0[8];
#pragma unroll
            for (int t = 0; t < 8; ++t) c0[t] = b4[t];
            float m1 = -INFINITY;
#pragma unroll
            for (int t = 0; t < 8; ++t)
                m1 = fmaxf(m1, fmaxf(fmaxf(c0[t].x, c0[t].y), fmaxf(c0[t].z, c0[t].w)));
            float s1 = 0.f;
#pragma unroll
            for (int t = 0; t < 8; ++t)
                s1 += expf(c0[t].x - m1) + expf(c0[t].y - m1) + expf(c0[t].z - m1) + expf(c0[t].w - m1);
#pragma unroll
            for (int t = 0; t < 8; ++t) c0[t] = b4[8 + t];
            float m2 = -INFINITY;
#pragma unroll
            for (int t = 0; t < 8; ++t)
                m2 = fmaxf(m2, fmaxf(fmaxf(c0[t].x, c0[t].y), fmaxf(c0[t].z, c0[t].w)));
            float s2 = 0.f;
#pragma unroll
            for (int t = 0; t < 8; ++t)
                s2 += expf(c0[t].x - m2) + expf(c0[t].y - m2) + expf(c0[t].z - m2) + expf(c0[t].w - m2);
            float M = fmaxf(m1, m2);
            float S = s1 * expf(m1 - M) + s2 * expf(m2 - M);
#pragma unroll
            for (int off = 1; off < 8; off <<= 1) {
                float oM = __shfl_xor(M, off);
                float oS = __shfl_xor(S, off);
                float Mn = fmaxf(M, oM);
                S = S * expf(M - Mn) + oS * expf(oM - Mn);
                M = Mn;
            }
            lse = M + logf(S);
            if (k == 0) tgval = base[s_tid[m]];
        }

        if (k == 0) {
            float nll = lse - tgval;
            float bcx = s_pbox[idx][0], bcy = s_pbox[idx][1];
            float bw  = s_pbox[idx][2], bh  = s_pbox[idx][3];
            float tcx = s_tgt[m][0], tcy = s_tgt[m][1], tw = s_tgt[m][2], th = s_tgt[m][3];
            float l1 = fabsf(bcx - tcx) + fabsf(bcy - tcy) + fabsf(bw - tw) + fabsf(bh - th);
            float ax0 = bcx - 0.5f * bw, ay0 = bcy - 0.5f * bh;
            float ax1 = bcx + 0.5f * bw, ay1 = bcy + 0.5f * bh;
            float tx0 = s_tgt[m][4], ty0 = s_tgt[m][5], tx1 = s_tgt[m][6], ty1 = s_tgt[m][7];
            float a1 = (ax1 - ax0) * (ay1 - ay0);
            float a2 = s_tgt[m][8];
            float iw = fmaxf(fminf(ax1, tx1) - fmaxf(ax0, tx0), 0.f);
            float ih = fmaxf(fminf(ay1, ty1) - fmaxf(ay0, ty0), 0.f);
            float inter = iw * ih;
            float uni = a1 + a2 - inter;
            float iou = inter / uni;
            float cw = fmaxf(fmaxf(ax1, tx1) - fminf(ax0, tx0), 0.f);
            float ch = fmaxf(fmaxf(ay1, ty1) - fminf(ay0, ty0), 0.f);
            float ac = cw * ch;
            float giou = iou - (ac - uni) / ac;
            s_pl1[m] = l1; s_pgi[m] = giou; s_pnl[m] = nll;
        }
    }
    __syncthreads();

    // ---- stage D: per-frame reduce, release-store, last block finalizes ----
    if (wave == 0) {
        float a = 0.f, b = 0.f, c = 0.f;
        if (lane < M_TGT) { a = s_pl1[lane]; b = s_pgi[lane]; c = s_pnl[lane]; }
#pragma unroll
        for (int off = 32; off > 0; off >>= 1) {
            a += __shfl_xor(a, off);
            b += __shfl_xor(b, off);
            c += __shfl_xor(c, off);
        }
        if (lane == 0) {
            __hip_atomic_store(&frame_part[f * 4 + 0], a, __ATOMIC_RELAXED, __HIP_MEMORY_SCOPE_AGENT);
            __hip_atomic_store(&frame_part[f * 4 + 1], b, __ATOMIC_RELAXED, __HIP_MEMORY_SCOPE_AGENT);
            __hip_atomic_store(&frame_part[f * 4 + 2], c, __ATOMIC_RELAXED, __HIP_MEMORY_SCOPE_AGENT);
            __threadfence();
            int old = atomicAdd(counter, 1);
            s_islast = (old == F_FRAMES - 1) ? 1 : 0;
        }
    }
    __syncthreads();

    if (s_islast) {
        __threadfence();
        float a = 0.f, b = 0.f, c = 0.f;
        if (tid < F_FRAMES) {
            a = __hip_atomic_load(&frame_part[tid * 4 + 0], __ATOMIC_RELAXED, __HIP_MEMORY_SCOPE_AGENT);
            b = __hip_atomic_load(&frame_part[tid * 4 + 1], __ATOMIC_RELAXED, __HIP_MEMORY_SCOPE_AGENT);
            c = __hip_atomic_load(&frame_part[tid * 4 + 2], __ATOMIC_RELAXED, __HIP_MEMORY_SCOPE_AGENT);
        }
#pragma unroll
        for (int off = 32; off > 0; off >>= 1) {
            a += __shfl_xor(a, off);
            b += __shfl_xor(b, off);
            c += __shfl_xor(c, off);
        }
        __shared__ float w[3][2];
        if (lane == 0 && wave < 2) { w[0][wave] = a; w[1][wave] = b; w[2][wave] = c; }
        __syncthreads();
        if (tid == 0) {
            constexpr float P = (float)(F_FRAMES * M_TGT);
            float S0 = w[0][0] + w[0][1];
            float S1 = w[1][0] + w[1][1];
            float S2 = w[2][0] + w[2][1];
            float l1  = S0 / (P * 4.f);
            float gl  = 1.f - S1 / P;
            float idl = S2 / P;
            out[0] = 5.f * l1 + 2.f * gl + 1.f * idl;   // + 2*0 cls
            out[1] = 0.f;
            out[2] = l1;
            out[3] = gl;
            out[4] = idl;
        }
    }
}

extern "C" void kernel_launch(void* const* d_in, const int* in_sizes, int n_in,
                              void* d_out, int out_size, void* d_ws, size_t ws_size,
                              hipStream_t stream) {
    const float* pl     = (const float*)d_in[0];   // pred_logits  [8,16,300,2]
    const float* pb     = (const float*)d_in[1];   // pred_boxes   [8,16,300,4]
    const float* il     = (const float*)d_in[2];   // id_logits    [8,16,300,512]
    const int*   labels = (const int*)d_in[3];     // target_labels [128,32]
    const float* tb     = (const float*)d_in[4];   // target_boxes  [128,32,4]
    const int*   tids   = (const int*)d_in[5];     // target_ids    [128,32]
    float* out = (float*)d_out;

    float* frame_part = (float*)d_ws;                          // [128,4] = 2 KB
    int*   counter    = (int*)((char*)d_ws + 4096);            // 4 B

    hipMemsetAsync(counter, 0, sizeof(int), stream);
    motip_fused_kernel<<<F_FRAMES, 256, 0, stream>>>(
        pl, pb, il, labels, tb, tids, frame_part, counter, out);
}